// Round 2
// baseline (1733.546 us; speedup 1.0000x reference)
//
#include <hip/hip_runtime.h>
#include <hip/hip_cooperative_groups.h>
#include <math.h>

namespace cg = cooperative_groups;

#define DIM 256
#define NEP 10000
#define D1 1024    // DIM*4
#define D2 512     // DIM*2
#define DE 4096    // COMP*DIM
#define KMAX 8
#define NBLK 1024  // cooperative grid: 4 blocks/CU x 256 CU

// ---- workspace layout (float element offsets) ----
#define OFF_P1   0                            // [1024][1024] gemv1 partials
#define OFF_P1A  (OFF_P1 + NBLK * D1)         // [64][1024]
#define OFF_H1   (OFF_P1A + 64 * D1)          // [1024]
#define OFF_P2   (OFF_H1 + D1)                // [64][512]
#define OFF_H2   (OFF_P2 + 64 * D2)           // [512]
#define OFF_P3   (OFF_H2 + D2)                // [16][4096]
#define OFF_ENC  (OFF_P3 + 16 * DE)           // [4096]
#define OFF_QN   (OFF_ENC + DE)               // [1] (padded 4)
#define OFF_SIMS (OFF_QN + 4)                 // [10000]
#define OFF_IDX  (OFF_SIMS + NEP)             // [8] ints
#define OFF_P4   (OFF_IDX + 8)                // [64][KMAX][512]
#define OFF_D    (OFF_P4 + 64 * KMAX * D2)    // [KMAX][512]
#define OFF_P5   (OFF_D + KMAX * D2)          // [16][256]

__device__ __forceinline__ float gelu_exact(float x) {
    return 0.5f * x * (1.0f + erff(x * 0.7071067811865476f));
}

// block-wide sum for 256 threads; all threads return the same value.
__device__ __forceinline__ float block_sum256(float v, float* red) {
    for (int o = 32; o > 0; o >>= 1) v += __shfl_down(v, o);
    __syncthreads();
    if ((threadIdx.x & 63) == 0) red[threadIdx.x >> 6] = v;
    __syncthreads();
    return red[0] + red[1] + red[2] + red[3];
}

__global__ __launch_bounds__(256, 4) void fused_episodic(
    const float* __restrict__ q, const float* __restrict__ ep,
    const float* __restrict__ W1, const float* __restrict__ b1,
    const float* __restrict__ g1, const float* __restrict__ be1,
    const float* __restrict__ W2, const float* __restrict__ b2,
    const float* __restrict__ g2, const float* __restrict__ be2,
    const float* __restrict__ W3, const float* __restrict__ b3,
    const float* __restrict__ Wd1, const float* __restrict__ bd1,
    const float* __restrict__ gd, const float* __restrict__ bed,
    const float* __restrict__ Wd2, const float* __restrict__ bd2,
    const int* __restrict__ kptr, float* __restrict__ ws,
    float* __restrict__ out)
{
    cg::grid_group grid = cg::this_grid();
    const int t = threadIdx.x;
    const int b = blockIdx.x;
    const int kk = min(kptr[0], KMAX);

    __shared__ float sstage[32];
    __shared__ float red[4];
    __shared__ float red2[4];
    __shared__ float bv[256];
    __shared__ int   bi[256];
    __shared__ float ssel[KMAX][64];
    __shared__ float sdb[32];

    // ---- Ph1: q @ W1 partials. 1024 blocks x 25 rows ----
    {
        if (t < 25) sstage[t] = q[b * 25 + t];
        __syncthreads();
        float4 acc = {0.f, 0.f, 0.f, 0.f};
        const float4* Wp = (const float4*)(W1 + (size_t)b * 25 * D1);
        #pragma unroll 5
        for (int i = 0; i < 25; ++i) {
            const float qv = sstage[i];
            const float4 w = Wp[i * 256 + t];
            acc.x += qv * w.x; acc.y += qv * w.y; acc.z += qv * w.z; acc.w += qv * w.w;
        }
        ((float4*)(ws + OFF_P1 + (size_t)b * D1))[t] = acc;
    }
    grid.sync();

    // ---- Ph2: reduce 1024 partials -> 64 groups ----
    if (b < 256) {
        const int pg = b >> 2, cc = b & 3;
        const int col = cc * 256 + t;
        float s = 0.f;
        #pragma unroll
        for (int j = 0; j < 16; ++j) s += ws[OFF_P1 + (size_t)(pg * 16 + j) * D1 + col];
        ws[OFF_P1A + pg * D1 + col] = s;
    }
    grid.sync();

    // ---- Ph3: final reduce + b1 + GELU + two-pass LN -> h1 ----
    if (b == 0) {
        float x[4];
        #pragma unroll
        for (int c = 0; c < 4; ++c) {
            const int col = c * 256 + t;
            float s = b1[col];
            for (int g = 0; g < 64; ++g) s += ws[OFF_P1A + g * D1 + col];
            x[c] = gelu_exact(s);
        }
        const float mu = block_sum256(x[0] + x[1] + x[2] + x[3], red) * (1.f / D1);
        float v = 0.f;
        #pragma unroll
        for (int c = 0; c < 4; ++c) { const float d = x[c] - mu; v += d * d; }
        const float var = block_sum256(v, red) * (1.f / D1);
        const float inv = rsqrtf(var + 1e-5f);
        #pragma unroll
        for (int c = 0; c < 4; ++c) {
            const int col = c * 256 + t;
            ws[OFF_H1 + col] = (x[c] - mu) * inv * g1[col] + be1[col];
        }
    }
    grid.sync();

    // ---- Ph4: h1 @ W2 partials. 64 blocks x 16 rows ----
    if (b < 64) {
        if (t < 16) sstage[t] = ws[OFF_H1 + b * 16 + t];
        __syncthreads();
        float2 acc = {0.f, 0.f};
        #pragma unroll 4
        for (int i = 0; i < 16; ++i) {
            const float hv = sstage[i];
            const float2 w = ((const float2*)(W2 + (size_t)(b * 16 + i) * D2))[t];
            acc.x += hv * w.x; acc.y += hv * w.y;
        }
        ((float2*)(ws + OFF_P2 + b * D2))[t] = acc;
    }
    grid.sync();

    // ---- Ph5: reduce + b2 + GELU + LN -> h2 ----
    if (b == 0) {
        float2 s = ((const float2*)b2)[t];
        for (int c = 0; c < 64; ++c) {
            const float2 p = ((const float2*)(ws + OFF_P2 + c * D2))[t];
            s.x += p.x; s.y += p.y;
        }
        const float x0 = gelu_exact(s.x), x1 = gelu_exact(s.y);
        const float mu = block_sum256(x0 + x1, red) * (1.f / D2);
        const float d0 = x0 - mu, d1 = x1 - mu;
        const float var = block_sum256(d0 * d0 + d1 * d1, red) * (1.f / D2);
        const float inv = rsqrtf(var + 1e-5f);
        ws[OFF_H2 + 2 * t]     = d0 * inv * g2[2 * t]     + be2[2 * t];
        ws[OFF_H2 + 2 * t + 1] = d1 * inv * g2[2 * t + 1] + be2[2 * t + 1];
    }
    grid.sync();

    // ---- Ph6: h2 @ W3 partials. 64 blocks = 16 rc x 4 cc, 32 rows each ----
    if (b < 64) {
        const int rc = b >> 2, cc = b & 3;
        if (t < 32) sstage[t] = ws[OFF_H2 + rc * 32 + t];
        __syncthreads();
        float4 acc = {0.f, 0.f, 0.f, 0.f};
        #pragma unroll 4
        for (int i = 0; i < 32; ++i) {
            const float hv = sstage[i];
            const float4 w = ((const float4*)(W3 + (size_t)(rc * 32 + i) * DE + cc * 1024))[t];
            acc.x += hv * w.x; acc.y += hv * w.y; acc.z += hv * w.z; acc.w += hv * w.w;
        }
        ((float4*)(ws + OFF_P3 + rc * DE + cc * 1024))[t] = acc;
    }
    grid.sync();

    // ---- Ph7: reduce -> enc + b3; ||enc|| ----
    if (b == 0) {
        float ss = 0.f;
        for (int c = 0; c < 16; ++c) {
            const int col = c * 256 + t;
            float s = b3[col];
            #pragma unroll
            for (int g = 0; g < 16; ++g) s += ws[OFF_P3 + g * DE + col];
            ws[OFF_ENC + col] = s;
            ss += s * s;
        }
        const float qn2 = block_sum256(ss, red);
        if (t == 0) ws[OFF_QN] = fmaxf(sqrtf(qn2), 1e-8f);
    }
    grid.sync();

    // ---- Ph8: cosine sims, grid-stride over episodes ----
    {
        const float4* encv = (const float4*)(ws + OFF_ENC);
        const float4 e0 = encv[t], e1 = encv[t + 256], e2 = encv[t + 512], e3 = encv[t + 768];
        const float qn = ws[OFF_QN];
        for (int e = b; e < NEP; e += NBLK) {
            const float4* row = (const float4*)(ep + (size_t)e * DE);
            const float4 a0 = row[t], a1 = row[t + 256], a2 = row[t + 512], a3 = row[t + 768];
            float dot = a0.x * e0.x + a0.y * e0.y + a0.z * e0.z + a0.w * e0.w
                      + a1.x * e1.x + a1.y * e1.y + a1.z * e1.z + a1.w * e1.w
                      + a2.x * e2.x + a2.y * e2.y + a2.z * e2.z + a2.w * e2.w
                      + a3.x * e3.x + a3.y * e3.y + a3.z * e3.z + a3.w * e3.w;
            float ssq = a0.x * a0.x + a0.y * a0.y + a0.z * a0.z + a0.w * a0.w
                      + a1.x * a1.x + a1.y * a1.y + a1.z * a1.z + a1.w * a1.w
                      + a2.x * a2.x + a2.y * a2.y + a2.z * a2.z + a2.w * a2.w
                      + a3.x * a3.x + a3.y * a3.y + a3.z * a3.z + a3.w * a3.w;
            for (int o = 32; o > 0; o >>= 1) {
                dot += __shfl_down(dot, o);
                ssq += __shfl_down(ssq, o);
            }
            __syncthreads();
            if ((t & 63) == 0) { red[t >> 6] = dot; red2[t >> 6] = ssq; }
            __syncthreads();
            if (t == 0) {
                const float dsum = red[0] + red[1] + red[2] + red[3];
                const float ssum = red2[0] + red2[1] + red2[2] + red2[3];
                const float en = fmaxf(sqrtf(ssum), 1e-8f);
                ws[OFF_SIMS + e] = dsum / (qn * en);
            }
        }
    }
    grid.sync();

    // ---- Ph9: top-k (k iterated argmax), block 0 ----
    if (b == 0) {
        int* idx = (int*)(ws + OFF_IDX);
        for (int p = 0; p < kk; ++p) {
            float best = -1e30f; int besti = 0;
            for (int j = t; j < NEP; j += 256) {
                const float v = ws[OFF_SIMS + j];
                if (v > best) { best = v; besti = j; }
            }
            bv[t] = best; bi[t] = besti;
            __syncthreads();
            for (int o = 128; o > 0; o >>= 1) {
                if (t < o) {
                    const float v2 = bv[t + o]; const int i2 = bi[t + o];
                    if (v2 > bv[t] || (v2 == bv[t] && i2 < bi[t])) { bv[t] = v2; bi[t] = i2; }
                }
                __syncthreads();
            }
            if (t == 0) { idx[p] = bi[0]; ws[OFF_SIMS + bi[0]] = -1e30f; }
            __syncthreads();
        }
    }
    grid.sync();

    // ---- Ph10: sel @ Wd1 partials. 64 blocks, i-chunks of 64 ----
    if (b < 64) {
        const int* idx = (const int*)(ws + OFF_IDX);
        const int i0 = b * 64;
        for (int x = t; x < kk * 64; x += 256) {
            const int r = x >> 6, ii = x & 63;
            ssel[r][ii] = ep[(size_t)idx[r] * DE + i0 + ii];
        }
        __syncthreads();
        float2 acc[KMAX];
        #pragma unroll
        for (int r = 0; r < KMAX; ++r) acc[r] = make_float2(0.f, 0.f);
        for (int i = 0; i < 64; ++i) {
            const float2 w = ((const float2*)(Wd1 + (size_t)(i0 + i) * D2))[t];
            #pragma unroll
            for (int r = 0; r < KMAX; ++r)
                if (r < kk) { const float sv = ssel[r][i]; acc[r].x += sv * w.x; acc[r].y += sv * w.y; }
        }
        for (int r = 0; r < kk; ++r)
            ((float2*)(ws + OFF_P4 + ((size_t)b * KMAX + r) * D2))[t] = acc[r];
    }
    grid.sync();

    // ---- Ph11: reduce + bd1 + GELU + LN per selected row ----
    if (b < kk) {
        float2 s = {0.f, 0.f};
        for (int c = 0; c < 64; ++c) {
            const float2 p = ((const float2*)(ws + OFF_P4 + ((size_t)c * KMAX + b) * D2))[t];
            s.x += p.x; s.y += p.y;
        }
        const float x0 = gelu_exact(s.x + bd1[2 * t]);
        const float x1 = gelu_exact(s.y + bd1[2 * t + 1]);
        const float mu = block_sum256(x0 + x1, red) * (1.f / D2);
        const float d0 = x0 - mu, d1 = x1 - mu;
        const float var = block_sum256(d0 * d0 + d1 * d1, red) * (1.f / D2);
        const float inv = rsqrtf(var + 1e-5f);
        ws[OFF_D + b * D2 + 2 * t]     = d0 * inv * gd[2 * t]     + bed[2 * t];
        ws[OFF_D + b * D2 + 2 * t + 1] = d1 * inv * gd[2 * t + 1] + bed[2 * t + 1];
    }
    grid.sync();

    // ---- Ph12: dbar chunk + matvec Wd2. 16 blocks, i-chunks of 32 ----
    if (b < 16) {
        if (t < 32) {
            float s = 0.f;
            for (int r = 0; r < kk; ++r) s += ws[OFF_D + r * D2 + b * 32 + t];
            sdb[t] = s / (float)kk;
        }
        __syncthreads();
        float acc = 0.f;
        #pragma unroll 8
        for (int i = 0; i < 32; ++i) acc += sdb[i] * Wd2[(size_t)(b * 32 + i) * DIM + t];
        ws[OFF_P5 + b * DIM + t] = acc;
    }
    grid.sync();

    // ---- Ph13: final sum + bd2 -> out ----
    if (b == 0) {
        float s = bd2[t];
        #pragma unroll
        for (int j = 0; j < 16; ++j) s += ws[OFF_P5 + j * DIM + t];
        out[t] = s;
    }
}

extern "C" void kernel_launch(void* const* d_in, const int* in_sizes, int n_in,
                              void* d_out, int out_size, void* d_ws, size_t ws_size,
                              hipStream_t stream) {
    const float* q   = (const float*)d_in[0];
    const float* ep  = (const float*)d_in[1];
    const float* W1  = (const float*)d_in[2];
    const float* b1  = (const float*)d_in[3];
    const float* g1  = (const float*)d_in[4];
    const float* be1 = (const float*)d_in[5];
    const float* W2  = (const float*)d_in[6];
    const float* b2  = (const float*)d_in[7];
    const float* g2  = (const float*)d_in[8];
    const float* be2 = (const float*)d_in[9];
    const float* W3  = (const float*)d_in[10];
    const float* b3  = (const float*)d_in[11];
    const float* Wd1 = (const float*)d_in[12];
    const float* bd1 = (const float*)d_in[13];
    const float* gd  = (const float*)d_in[14];
    const float* bed = (const float*)d_in[15];
    const float* Wd2 = (const float*)d_in[16];
    const float* bd2 = (const float*)d_in[17];
    const int*   kp  = (const int*)d_in[18];
    float* ws  = (float*)d_ws;
    float* out = (float*)d_out;

    void* args[] = { (void*)&q, (void*)&ep, (void*)&W1, (void*)&b1, (void*)&g1, (void*)&be1,
                     (void*)&W2, (void*)&b2, (void*)&g2, (void*)&be2,
                     (void*)&W3, (void*)&b3, (void*)&Wd1, (void*)&bd1, (void*)&gd, (void*)&bed,
                     (void*)&Wd2, (void*)&bd2, (void*)&kp, (void*)&ws, (void*)&out };
    hipLaunchCooperativeKernel((const void*)fused_episodic, dim3(NBLK), dim3(256),
                               args, 0, stream);
}